// Round 5
// baseline (299.429 us; speedup 1.0000x reference)
//
#include <hip/hip_runtime.h>

// x: [B,H,S,16] fp32, rows = 262144
// out per row: [1, x*0.5, (x_i*x_j)*0.176776695] -> 273 floats (fp32)
// Block = 256 threads handles 64 rows: 64*273 = 17472 floats = 4368 float4,
// contiguous + 16B-aligned. x staged in LDS with row stride 17
// (slot 16 = 1.0f) so the decode is fully branchless: val = A*B*S.

#define FDIM 16
#define OUT_PER_ROW 273
#define ROWS_PER_BLOCK 64
#define ROW_STRIDE 17                                  // 16 x-values + 1.0f slot
#define SUPER_FLOATS (ROWS_PER_BLOCK * OUT_PER_ROW)    // 17472
#define SUPER_VEC4   (SUPER_FLOATS / 4)                // 4368 = 17*256 + 16
#define X_VEC4       (ROWS_PER_BLOCK * FDIM / 4)       // 256

typedef float fvec4 __attribute__((ext_vector_type(4)));

__global__ __launch_bounds__(256) void based_feature_kernel(
    const float* __restrict__ x, float* __restrict__ out)
{
    constexpr float C2 = 0.17677669529663687f;         // 1/(sqrt(2)*4)

    __shared__ float xs[ROWS_PER_BLOCK * ROW_STRIDE];  // 4352 B

    const int t  = threadIdx.x;
    const int sc = blockIdx.x;

    // stage 64 rows (4 KB) — each thread loads one float4, scatters to stride-17 rows
    {
        const fvec4* x4 = reinterpret_cast<const fvec4*>(x) + (size_t)sc * X_VEC4;
        fvec4 v = x4[t];
        const int row = t >> 2;                        // 4 float4 per row
        const int col = (t & 3) * 4;
        float* dst = &xs[row * ROW_STRIDE + col];
        dst[0] = v[0]; dst[1] = v[1]; dst[2] = v[2]; dst[3] = v[3];
        if (t < ROWS_PER_BLOCK) xs[t * ROW_STRIDE + FDIM] = 1.0f;
    }
    __syncthreads();

    fvec4* out4 = reinterpret_cast<fvec4*>(out) + (size_t)sc * SUPER_VEC4;

#pragma unroll 2
    for (int p = 0; p < 18; ++p) {
        const int q = p * 256 + t;
        if (q < SUPER_VEC4) {
            const int f0 = q * 4;
            fvec4 v;
#pragma unroll
            for (int e = 0; e < 4; ++e) {
                const int f  = f0 + e;
                const int r  = f / OUT_PER_ROW;        // 0..63 (magic-mul)
                const int k  = f - r * OUT_PER_ROW;    // 0..272
                const int kk = k - (FDIM + 1);         // >=0 for quadratic part
                const bool isq = kk >= 0;
                const int iA = isq ? (kk >> 4) : (k > 0 ? k - 1 : FDIM);
                const int iB = isq ? (kk & 15) : FDIM; // slot 16 = 1.0f
                const float S = isq ? C2 : (k > 0 ? 0.5f : 1.0f);
                const float* xr = &xs[r * ROW_STRIDE];
                v[e] = xr[iA] * xr[iB] * S;
            }
            out4[q] = v;                               // plain cached dwordx4 store
        }
    }
}

extern "C" void kernel_launch(void* const* d_in, const int* in_sizes, int n_in,
                              void* d_out, int out_size, void* d_ws, size_t ws_size,
                              hipStream_t stream) {
    const float* x = (const float*)d_in[0];
    float* out = (float*)d_out;

    const int total_x = in_sizes[0];                   // B*H*S*16
    const int nrows   = total_x / FDIM;                // 262144
    const int nsuper  = nrows / ROWS_PER_BLOCK;        // 4096

    based_feature_kernel<<<dim3(nsuper), dim3(256), 0, stream>>>(x, out);
}